// Round 7
// baseline (280.954 us; speedup 1.0000x reference)
//
#include <hip/hip_runtime.h>
#include <hip/hip_bf16.h>

#define B_ 8
#define L_ 512
#define N_ 2048
#define C_ 1024
#define D_ 128

typedef __attribute__((ext_vector_type(8))) short    short8;   // 8 x bf16 bits
typedef __attribute__((ext_vector_type(4))) short    short4v;  // 4 x bf16 bits (8B)
typedef __attribute__((ext_vector_type(8))) _Float16 half8;
typedef __attribute__((ext_vector_type(4))) float    floatx4;

static __device__ __forceinline__ float s2f(short s) {
    return __uint_as_float(((unsigned)(unsigned short)s) << 16);
}
static __device__ __forceinline__ short f2bf(float f) {
    union { __hip_bfloat16 h; short s; } u;
    u.h = __float2bfloat16(f);
    return u.s;
}

struct F8 { float v[8]; };

static __device__ __forceinline__ F8 load8(const void* raw, long off, int is_bf16) {
    F8 r;
    if (is_bf16) {
        short8 x = *reinterpret_cast<const short8*>((const short*)raw + off);
        #pragma unroll
        for (int i = 0; i < 8; ++i) r.v[i] = s2f(x[i]);
    } else {
        const float* p = (const float*)raw + off;
        float4 a = *reinterpret_cast<const float4*>(p);
        float4 b = *reinterpret_cast<const float4*>(p + 4);
        r.v[0]=a.x; r.v[1]=a.y; r.v[2]=a.z; r.v[3]=a.w;
        r.v[4]=b.x; r.v[5]=b.y; r.v[6]=b.z; r.v[7]=b.w;
    }
    return r;
}

static __device__ __forceinline__ float bias_at(const void* raw, int d, int is_bf16) {
    return is_bf16 ? s2f(((const short*)raw)[d]) : ((const float*)raw)[d];
}

static __device__ __forceinline__ void load_lds16(const void* g, void* l) {
    __builtin_amdgcn_global_load_lds(
        (const __attribute__((address_space(1))) void*)g,
        (__attribute__((address_space(3))) void*)l, 16, 0, 0);
}

// ---------------------------------------------------------------------------
// Dtype detection (fp32 vs bf16 world).
// ---------------------------------------------------------------------------
__global__ void detect_kernel(const unsigned* __restrict__ words, int* __restrict__ flag) {
    int cnt = 0;
    for (int i = threadIdx.x; i < 256; i += 64) {
        float lowv = __uint_as_float(words[i] << 16);
        float a = fabsf(lowv);
        if (a >= 1e-5f && a <= 100.0f) cnt++;
    }
    #pragma unroll
    for (int off = 32; off; off >>= 1) cnt += __shfl_down(cnt, off);
    if (threadIdx.x == 0) flag[0] = (cnt > 128) ? 1 : 0;
}

// ---------------------------------------------------------------------------
// fp32 world only: raw fp32 -> bf16 bits.
// ---------------------------------------------------------------------------
__global__ __launch_bounds__(256) void cvt_kernel(const void* __restrict__ in_raw,
                                                  short* __restrict__ out, long n,
                                                  const int* __restrict__ flag) {
    if (*flag) return;
    long i = ((long)blockIdx.x * 256 + threadIdx.x) * 8;
    if (i >= n) return;
    F8 x = load8(in_raw, i, 0);
    short8 o;
    #pragma unroll
    for (int j = 0; j < 8; ++j) o[j] = f2bf(x.v[j]);
    *reinterpret_cast<short8*>(out + i) = o;
}

// ---------------------------------------------------------------------------
// fp32 world only: raw fp32 -> fp16 for BOTH weight matrices (merged launch).
// ---------------------------------------------------------------------------
__global__ __launch_bounds__(256) void cvt_half2_kernel(
    const void* __restrict__ a_raw, _Float16* __restrict__ a_out,
    const void* __restrict__ b_raw, _Float16* __restrict__ b_out,
    long n, const int* __restrict__ flag) {
    if (*flag) return;
    const void* in  = blockIdx.y ? b_raw : a_raw;
    _Float16*   out = blockIdx.y ? b_out : a_out;
    long i = ((long)blockIdx.x * 256 + threadIdx.x) * 8;
    if (i >= n) return;
    F8 x = load8(in, i, 0);
    half8 o;
    #pragma unroll
    for (int j = 0; j < 8; ++j) o[j] = (_Float16)x.v[j];
    *reinterpret_cast<half8*>(out + i) = o;
}

// ---------------------------------------------------------------------------
// Kernel 1: Q = F @ Wq^T + bq ; K = F @ Wk^T + bk  (fp16 out) — MERGED.
// BK=64 + double-buffered LDS, ONE barrier per K-step (16 total vs 64).
// Staging for step kb+1 is issued BEFORE compute of step kb; the end-of-iter
// barrier's vmcnt/lgkmcnt drain guarantees it landed.
// LDS rows are 64 shorts (128B = 8 x 16B slots); XOR swizzle slot^(row&7):
// phys slot p of row r holds logical group p^(r&7); achieved via source-side
// pre-swizzle (linear LDS dst for global_load_lds), same involution on read.
// LDS: Ft 2x8KB + Wt 2x32KB = 80KB -> 1 block/CU (grid 256 = 1/CU).
// ---------------------------------------------------------------------------
__global__ __launch_bounds__(512) void proj_kernel(
    const void* __restrict__ Fraw,
    const void* __restrict__ Wq_raw, const void* __restrict__ Wk_raw,
    const _Float16* __restrict__ Wq_h, const _Float16* __restrict__ Wk_h,
    const void* __restrict__ bq_raw, const void* __restrict__ bk_raw,
    _Float16* __restrict__ Q, _Float16* __restrict__ K,
    const int* __restrict__ flag)
{
    const int is_bf16 = *flag;
    const int tid  = threadIdx.x;
    const int wave = tid >> 6;
    const int lane = tid & 63;
    const int quad = lane >> 4;
    const int l16  = lane & 15;
    const long r0  = (long)blockIdx.x * 64;

    const int m0   = (wave & 1) * 32;    // F rows within tile
    const int col0 = (wave >> 1) * 64;   // W rows within 256 (Q|K)

    __shared__ short Ft[2][64 * 64];     // 2 x 8 KB
    __shared__ short Wt[2][256 * 64];    // 2 x 32 KB

    floatx4 acc[2][4] = {};

    // staging lane map: 8-row chunks of 64 shorts; lane covers row srow,
    // phys 16B slot sslot; fetch logical group sslot^srow (source swizzle).
    const int srow  = lane >> 3;         // 0..7
    const int sslot = lane & 7;          // 0..7
    const int skoff = (sslot ^ srow) * 8;

    if (is_bf16) {
        const short* Fr  = (const short*)Fraw;
        const short* Wqr = (const short*)Wq_raw;
        const short* Wkr = (const short*)Wk_raw;

        auto STAGE = [&](int kb, int buf) {
            const int k0 = kb * 64;
            // W: 32 chunks of 8 rows; wave stages chunks wave*4 .. wave*4+3
            #pragma unroll
            for (int j = 0; j < 4; ++j) {
                const int c = wave * 4 + j;               // 0..31
                const short* Wr = (c < 16) ? Wqr : Wkr;
                const int wrow = (c & 15) * 8 + srow;     // 0..127
                load_lds16(Wr + (long)wrow * C_ + k0 + skoff,
                           Wt[buf] + c * 512 + lane * 8);
            }
            // F: 8 chunks of 8 rows; wave stages chunk `wave`
            load_lds16(Fr + (r0 + wave * 8 + srow) * (long)C_ + k0 + skoff,
                       Ft[buf] + wave * 512 + lane * 8);
        };

        STAGE(0, 0);
        __syncthreads();
        for (int kb = 0; kb < 16; ++kb) {
            const int buf = kb & 1;
            if (kb < 15) STAGE(kb + 1, buf ^ 1);
            #pragma unroll
            for (int kk = 0; kk < 2; ++kk) {
                short8 af[2], bfr[4];
                #pragma unroll
                for (int t = 0; t < 2; ++t) {
                    const int row = m0 + t * 16 + l16;
                    const int ph  = (kk * 4 + quad) ^ (row & 7);
                    af[t] = *reinterpret_cast<const short8*>(Ft[buf] + row * 64 + ph * 8);
                }
                #pragma unroll
                for (int u = 0; u < 4; ++u) {
                    const int wrow = col0 + u * 16 + l16;
                    const int ph   = (kk * 4 + quad) ^ (wrow & 7);
                    bfr[u] = *reinterpret_cast<const short8*>(Wt[buf] + wrow * 64 + ph * 8);
                }
                #pragma unroll
                for (int t = 0; t < 2; ++t)
                    #pragma unroll
                    for (int u = 0; u < 4; ++u)
                        acc[t][u] = __builtin_amdgcn_mfma_f32_16x16x32_bf16(af[t], bfr[u], acc[t][u], 0, 0, 0);
            }
            __syncthreads();
        }
    } else {
        _Float16* FtH0 = (_Float16*)Ft[0];
        _Float16* FtH1 = (_Float16*)Ft[1];
        _Float16* WtH0 = (_Float16*)Wt[0];
        _Float16* WtH1 = (_Float16*)Wt[1];

        // F register-staging map: 8 threads per row, 8 fp32 (=16B out) each
        const int frow = tid >> 3;                 // 0..63
        const int fseg = tid & 7;                  // 0..7
        const int fph  = fseg ^ (frow & 7);        // phys slot

        auto STAGE = [&](int kb, int buf) {
            const int k0 = kb * 64;
            _Float16* Wth = buf ? WtH1 : WtH0;
            _Float16* Fth = buf ? FtH1 : FtH0;
            #pragma unroll
            for (int j = 0; j < 4; ++j) {
                const int c = wave * 4 + j;
                const _Float16* Wh = (c < 16) ? Wq_h : Wk_h;
                const int wrow = (c & 15) * 8 + srow;
                load_lds16(Wh + (long)wrow * C_ + k0 + skoff,
                           Wth + c * 512 + lane * 8);
            }
            // F: all 512 threads, 8 fp32 -> 8 fp16 (one 16B group each)
            F8 x = load8(Fraw, (r0 + frow) * (long)C_ + k0 + fseg * 8, 0);
            half8 h;
            #pragma unroll
            for (int j = 0; j < 8; ++j) h[j] = (_Float16)x.v[j];
            *reinterpret_cast<half8*>(Fth + frow * 64 + fph * 8) = h;
        };

        STAGE(0, 0);
        __syncthreads();
        for (int kb = 0; kb < 16; ++kb) {
            const int buf = kb & 1;
            if (kb < 15) STAGE(kb + 1, buf ^ 1);
            _Float16* Wth = buf ? WtH1 : WtH0;
            _Float16* Fth = buf ? FtH1 : FtH0;
            #pragma unroll
            for (int kk = 0; kk < 2; ++kk) {
                half8 af[2], bfr[4];
                #pragma unroll
                for (int t = 0; t < 2; ++t) {
                    const int row = m0 + t * 16 + l16;
                    const int ph  = (kk * 4 + quad) ^ (row & 7);
                    af[t] = *reinterpret_cast<const half8*>(Fth + row * 64 + ph * 8);
                }
                #pragma unroll
                for (int u = 0; u < 4; ++u) {
                    const int wrow = col0 + u * 16 + l16;
                    const int ph   = (kk * 4 + quad) ^ (wrow & 7);
                    bfr[u] = *reinterpret_cast<const half8*>(Wth + wrow * 64 + ph * 8);
                }
                #pragma unroll
                for (int t = 0; t < 2; ++t)
                    #pragma unroll
                    for (int u = 0; u < 4; ++u)
                        acc[t][u] = __builtin_amdgcn_mfma_f32_16x16x32_f16(af[t], bfr[u], acc[t][u], 0, 0, 0);
            }
            __syncthreads();
        }
    }

    const bool isK = (col0 >= 128);
    const void* braw = isK ? bk_raw : bq_raw;
    _Float16* Out    = isK ? K : Q;
    #pragma unroll
    for (int u = 0; u < 4; ++u) {
        const int d = (col0 + u * 16 + l16) & 127;
        const float bv = bias_at(braw, d, is_bf16);
        #pragma unroll
        for (int t = 0; t < 2; ++t)
            #pragma unroll
            for (int r = 0; r < 4; ++r) {
                const long row = r0 + m0 + t * 16 + quad * 4 + r;
                Out[row * D_ + d] = (_Float16)(acc[t][u][r] + bv);
            }
    }
}

// ---------------------------------------------------------------------------
// Kernel 2 (FUSED attn+xm) — round-2 structure with two latency fixes:
//  (a) K fragments batched (kf[4] back-to-back 16B loads) and PREFETCHED for
//      ch+1 into the same registers right after E^T's last use.
//  (b) logits al[4][4] preload issued FIRST in the chunk.
// FIXED (r7): al load had `quad*8` added twice (Lw already contains it) ->
// quads 1-3 read logits shifted by 8/16/24 columns -> absmax 6.97. Removed.
// ---------------------------------------------------------------------------
__global__ __launch_bounds__(512, 2) void fused_attn_xm_kernel(
    const void* __restrict__ Lraw,   // [B,L,N] raw (bf16 world)
    const short* __restrict__ Lcvt,  // [B,L,N] bf16 bits (fp32 world)
    const _Float16* __restrict__ Q,  // [B,N,D] fp16
    const _Float16* __restrict__ K,  // [B,N,D] fp16
    void* __restrict__ OutRaw,
    const int* __restrict__ flag)
{
    const int is_bf16 = *flag;
    const int f    = blockIdx.y * 32 + blockIdx.x;   // flat dispatch index
    const int b    = f & 7;                           // XCD-affinity: batch = f % 8
    const int m0   = (f >> 3) * 64;                   // m-tile base
    const int wave = threadIdx.x >> 6;
    const int lane = threadIdx.x & 63;
    const int quad = lane >> 4;
    const int l16  = lane & 15;

    __shared__ short P0[64 * 128];   // 16 KB
    __shared__ short P1[64 * 128];   // 16 KB
    __shared__ float Zs[64];

    if (threadIdx.x < 64) Zs[threadIdx.x] = 0.0f;

    const short*    Lb = (is_bf16 ? (const short*)Lraw : Lcvt) + (long)b * L_ * N_;
    const _Float16* Qb = Q + (long)b * N_ * D_;
    const _Float16* Kb = K + (long)b * N_ * D_;

    // Q fragments (B-operand of E^T): m = m0 + u*16 + l16, d = s*32 + quad*8
    half8 bq[4][4];
    #pragma unroll
    for (int u = 0; u < 4; ++u)
        #pragma unroll
        for (int s = 0; s < 4; ++s)
            bq[u][s] = *reinterpret_cast<const half8*>(
                Qb + (long)(m0 + u * 16 + l16) * D_ + s * 32 + quad * 8);

    const int lw  = wave * 64;        // this wave's l-rows
    const int swz = l16 * 2;          // even XOR keeps 16B accesses contiguous
    const short* Lw = Lb + (long)(lw + l16) * N_ + quad * 8;           // logits base (incl quad*8)
    const _Float16* Kw = Kb + (long)(wave * 16 + l16) * D_ + quad * 8; // K base (incl quad*8)
    // P write slot: logical 8B slot = wave*4 + quad (n_local/4); phys = slot ^ swz
    const int pwr = ((wave * 4 + quad) ^ swz) << 2;

    floatx4 acc[4][4] = {};           // [t: l-frag][u: m-frag]
    float zpart[4] = {};

    // K fragments for chunk 0 (batched)
    half8 kf[4];
    #pragma unroll
    for (int s = 0; s < 4; ++s)
        kf[s] = *reinterpret_cast<const half8*>(Kw + s * 32);

    #pragma unroll 2
    for (int ch = 0; ch < 16; ++ch) {
        const int n0 = ch * 128;
        short* Pb = (ch & 1) ? P1 : P0;

        // ---- 1. logits full-chunk preload (consumed after the barrier) ----
        // NOTE: Lw already includes quad*8 — do NOT add it again.
        short8 al[4][4];
        #pragma unroll
        for (int t = 0; t < 4; ++t)
            #pragma unroll
            for (int ks = 0; ks < 4; ++ks)
                al[t][ks] = *reinterpret_cast<const short8*>(
                    Lw + (long)t * 16 * N_ + n0 + ks * 32);

        // ---- 2. E^T with resident kf: lane holds
        // E[n0+wave*16+quad*4+r][m0+u*16+l16] in ae[u][r]
        floatx4 ae[4] = {};
        #pragma unroll
        for (int s = 0; s < 4; ++s)
            #pragma unroll
            for (int u = 0; u < 4; ++u)
                ae[u] = __builtin_amdgcn_mfma_f32_16x16x32_f16(kf[s], bq[u][s], ae[u], 0, 0, 0);

        // ---- 3. prefetch K for chunk ch+1 (same regs; hides under 4-6) ----
        if (ch < 15) {
            const _Float16* krow = Kw + (long)(n0 + 128) * D_;
            #pragma unroll
            for (int s = 0; s < 4; ++s)
                kf[s] = *reinterpret_cast<const half8*>(krow + s * 32);
        }

        // ---- 4. exp, Z partials, pack 4 consecutive-n bf16, swizzled write
        #pragma unroll
        for (int u = 0; u < 4; ++u) {
            short4v pk;
            #pragma unroll
            for (int r = 0; r < 4; ++r) {
                float e = __expf(ae[u][r]);
                zpart[u] += e;
                pk[r] = f2bf(e);
            }
            *reinterpret_cast<short4v*>(Pb + (u * 16 + l16) * 128 + pwr) = pk;
        }
        __syncthreads();   // write(ch) -> read(ch); dbuf covers read->next-write

        // ---- 5. out-GEMM: acc[t][u] += L[l, n-chunk] · P[m, n-chunk]^T ----
        #pragma unroll
        for (int ks = 0; ks < 4; ++ks) {
            short8 bp[4];
            #pragma unroll
            for (int u = 0; u < 4; ++u) {
                const int m = u * 16 + l16;
                bp[u] = *reinterpret_cast<const short8*>(
                    Pb + m * 128 + ((((ks * 8 + quad * 2) ^ swz)) << 2));
            }
            #pragma unroll
            for (int t = 0; t < 4; ++t)
                #pragma unroll
                for (int u = 0; u < 4; ++u)
                    acc[t][u] = __builtin_amdgcn_mfma_f32_16x16x32_bf16(
                        al[t][ks], bp[u], acc[t][u], 0, 0, 0);
        }
    }

    // ---- Z: reduce quads within wave, then waves via LDS atomics ----
    #pragma unroll
    for (int u = 0; u < 4; ++u) {
        float z = zpart[u];
        z += __shfl_xor(z, 16);
        z += __shfl_xor(z, 32);
        if (lane < 16) atomicAdd(&Zs[u * 16 + lane], z);
    }
    __syncthreads();

    float invz[4];
    #pragma unroll
    for (int u = 0; u < 4; ++u) invz[u] = 1.0f / Zs[u * 16 + l16];

    // ---- epilogue: divide by Z and store ----
    if (is_bf16) {
        short* Ob = (short*)OutRaw + (long)b * L_ * N_;
        #pragma unroll
        for (int t = 0; t < 4; ++t)
            #pragma unroll
            for (int u = 0; u < 4; ++u)
                #pragma unroll
                for (int r = 0; r < 4; ++r) {
                    const long row = lw + t * 16 + quad * 4 + r;
                    const int  col = m0 + u * 16 + l16;
                    Ob[row * N_ + col] = f2bf(acc[t][u][r] * invz[u]);
                }
    } else {
        float* Ob = (float*)OutRaw + (long)b * L_ * N_;
        #pragma unroll
        for (int t = 0; t < 4; ++t)
            #pragma unroll
            for (int u = 0; u < 4; ++u)
                #pragma unroll
                for (int r = 0; r < 4; ++r) {
                    const long row = lw + t * 16 + quad * 4 + r;
                    const int  col = m0 + u * 16 + l16;
                    Ob[row * N_ + col] = acc[t][u][r] * invz[u];
                }
    }
}

// ---------------------------------------------------------------------------
extern "C" void kernel_launch(void* const* d_in, const int* in_sizes, int n_in,
                              void* d_out, int out_size, void* d_ws, size_t ws_size,
                              hipStream_t stream) {
    const void* logits_raw = d_in[0];
    const void* feats_raw  = d_in[1];
    const void* wq_raw     = d_in[2];
    const void* bq_raw     = d_in[3];
    const void* wk_raw     = d_in[4];
    const void* bk_raw     = d_in[5];

    char* ws = (char*)d_ws;
    size_t off = 0;
    int* flag = (int*)(ws + off);           off += 256;
    short* logb = (short*)(ws + off);       off += (size_t)B_ * L_ * N_ * 2;   // 16 MB
    _Float16* Wq_h = (_Float16*)(ws + off); off += (size_t)D_ * C_ * 2;
    _Float16* Wk_h = (_Float16*)(ws + off); off += (size_t)D_ * C_ * 2;
    _Float16* Q = (_Float16*)(ws + off);    off += (size_t)B_ * N_ * D_ * 2;   // 4 MB
    _Float16* K = (_Float16*)(ws + off);    off += (size_t)B_ * N_ * D_ * 2;   // 4 MB

    hipLaunchKernelGGL(detect_kernel, dim3(1), dim3(64), 0, stream,
                       (const unsigned*)feats_raw, flag);
    hipLaunchKernelGGL(cvt_kernel, dim3((B_ * L_ * N_) / (256 * 8)), dim3(256), 0, stream,
                       logits_raw, logb, (long)B_ * L_ * N_, flag);
    hipLaunchKernelGGL(cvt_half2_kernel, dim3((D_ * C_) / (256 * 8), 2), dim3(256), 0, stream,
                       wq_raw, Wq_h, wk_raw, Wk_h, (long)D_ * C_, flag);
    hipLaunchKernelGGL(proj_kernel, dim3(B_ * N_ / 64), dim3(512), 0, stream,
                       feats_raw, wq_raw, wk_raw, Wq_h, Wk_h, bq_raw, bk_raw, Q, K, flag);
    hipLaunchKernelGGL(fused_attn_xm_kernel, dim3(N_ / 64, B_), dim3(512), 0, stream,
                       logits_raw, logb, Q, K, d_out, flag);
}

// Round 8
// 229.738 us; speedup vs baseline: 1.2229x; 1.2229x over previous
//
#include <hip/hip_runtime.h>
#include <hip/hip_bf16.h>

#define B_ 8
#define L_ 512
#define N_ 2048
#define C_ 1024
#define D_ 128

typedef __attribute__((ext_vector_type(8))) short    short8;   // 8 x bf16 bits
typedef __attribute__((ext_vector_type(4))) short    short4v;  // 4 x bf16 bits (8B)
typedef __attribute__((ext_vector_type(8))) _Float16 half8;
typedef __attribute__((ext_vector_type(4))) float    floatx4;

static __device__ __forceinline__ float s2f(short s) {
    return __uint_as_float(((unsigned)(unsigned short)s) << 16);
}
static __device__ __forceinline__ short f2bf(float f) {
    union { __hip_bfloat16 h; short s; } u;
    u.h = __float2bfloat16(f);
    return u.s;
}

struct F8 { float v[8]; };

static __device__ __forceinline__ F8 load8(const void* raw, long off, int is_bf16) {
    F8 r;
    if (is_bf16) {
        short8 x = *reinterpret_cast<const short8*>((const short*)raw + off);
        #pragma unroll
        for (int i = 0; i < 8; ++i) r.v[i] = s2f(x[i]);
    } else {
        const float* p = (const float*)raw + off;
        float4 a = *reinterpret_cast<const float4*>(p);
        float4 b = *reinterpret_cast<const float4*>(p + 4);
        r.v[0]=a.x; r.v[1]=a.y; r.v[2]=a.z; r.v[3]=a.w;
        r.v[4]=b.x; r.v[5]=b.y; r.v[6]=b.z; r.v[7]=b.w;
    }
    return r;
}

static __device__ __forceinline__ float bias_at(const void* raw, int d, int is_bf16) {
    return is_bf16 ? s2f(((const short*)raw)[d]) : ((const float*)raw)[d];
}

static __device__ __forceinline__ void load_lds16(const void* g, void* l) {
    __builtin_amdgcn_global_load_lds(
        (const __attribute__((address_space(1))) void*)g,
        (__attribute__((address_space(3))) void*)l, 16, 0, 0);
}

// ---------------------------------------------------------------------------
// Dtype detection (fp32 vs bf16 world).
// ---------------------------------------------------------------------------
__global__ void detect_kernel(const unsigned* __restrict__ words, int* __restrict__ flag) {
    int cnt = 0;
    for (int i = threadIdx.x; i < 256; i += 64) {
        float lowv = __uint_as_float(words[i] << 16);
        float a = fabsf(lowv);
        if (a >= 1e-5f && a <= 100.0f) cnt++;
    }
    #pragma unroll
    for (int off = 32; off; off >>= 1) cnt += __shfl_down(cnt, off);
    if (threadIdx.x == 0) flag[0] = (cnt > 128) ? 1 : 0;
}

// ---------------------------------------------------------------------------
// fp32 world only: raw fp32 -> bf16 bits.
// ---------------------------------------------------------------------------
__global__ __launch_bounds__(256) void cvt_kernel(const void* __restrict__ in_raw,
                                                  short* __restrict__ out, long n,
                                                  const int* __restrict__ flag) {
    if (*flag) return;
    long i = ((long)blockIdx.x * 256 + threadIdx.x) * 8;
    if (i >= n) return;
    F8 x = load8(in_raw, i, 0);
    short8 o;
    #pragma unroll
    for (int j = 0; j < 8; ++j) o[j] = f2bf(x.v[j]);
    *reinterpret_cast<short8*>(out + i) = o;
}

// ---------------------------------------------------------------------------
// fp32 world only: raw fp32 -> fp16 for BOTH weight matrices (merged launch).
// ---------------------------------------------------------------------------
__global__ __launch_bounds__(256) void cvt_half2_kernel(
    const void* __restrict__ a_raw, _Float16* __restrict__ a_out,
    const void* __restrict__ b_raw, _Float16* __restrict__ b_out,
    long n, const int* __restrict__ flag) {
    if (*flag) return;
    const void* in  = blockIdx.y ? b_raw : a_raw;
    _Float16*   out = blockIdx.y ? b_out : a_out;
    long i = ((long)blockIdx.x * 256 + threadIdx.x) * 8;
    if (i >= n) return;
    F8 x = load8(in, i, 0);
    half8 o;
    #pragma unroll
    for (int j = 0; j < 8; ++j) o[j] = (_Float16)x.v[j];
    *reinterpret_cast<half8*>(out + i) = o;
}

// ---------------------------------------------------------------------------
// Kernel 1: Q = F @ Wq^T + bq ; K = F @ Wk^T + bk  (fp16 out) — MERGED.
// BK=64 + double-buffered LDS, ONE barrier per K-step.
// ---------------------------------------------------------------------------
__global__ __launch_bounds__(512) void proj_kernel(
    const void* __restrict__ Fraw,
    const void* __restrict__ Wq_raw, const void* __restrict__ Wk_raw,
    const _Float16* __restrict__ Wq_h, const _Float16* __restrict__ Wk_h,
    const void* __restrict__ bq_raw, const void* __restrict__ bk_raw,
    _Float16* __restrict__ Q, _Float16* __restrict__ K,
    const int* __restrict__ flag)
{
    const int is_bf16 = *flag;
    const int tid  = threadIdx.x;
    const int wave = tid >> 6;
    const int lane = tid & 63;
    const int quad = lane >> 4;
    const int l16  = lane & 15;
    const long r0  = (long)blockIdx.x * 64;

    const int m0   = (wave & 1) * 32;    // F rows within tile
    const int col0 = (wave >> 1) * 64;   // W rows within 256 (Q|K)

    __shared__ short Ft[2][64 * 64];     // 2 x 8 KB
    __shared__ short Wt[2][256 * 64];    // 2 x 32 KB

    floatx4 acc[2][4] = {};

    // staging lane map: 8-row chunks of 64 shorts; lane covers row srow,
    // phys 16B slot sslot; fetch logical group sslot^srow (source swizzle).
    const int srow  = lane >> 3;         // 0..7
    const int sslot = lane & 7;          // 0..7
    const int skoff = (sslot ^ srow) * 8;

    if (is_bf16) {
        const short* Fr  = (const short*)Fraw;
        const short* Wqr = (const short*)Wq_raw;
        const short* Wkr = (const short*)Wk_raw;

        auto STAGE = [&](int kb, int buf) {
            const int k0 = kb * 64;
            #pragma unroll
            for (int j = 0; j < 4; ++j) {
                const int c = wave * 4 + j;               // 0..31
                const short* Wr = (c < 16) ? Wqr : Wkr;
                const int wrow = (c & 15) * 8 + srow;     // 0..127
                load_lds16(Wr + (long)wrow * C_ + k0 + skoff,
                           Wt[buf] + c * 512 + lane * 8);
            }
            load_lds16(Fr + (r0 + wave * 8 + srow) * (long)C_ + k0 + skoff,
                       Ft[buf] + wave * 512 + lane * 8);
        };

        STAGE(0, 0);
        __syncthreads();
        for (int kb = 0; kb < 16; ++kb) {
            const int buf = kb & 1;
            if (kb < 15) STAGE(kb + 1, buf ^ 1);
            #pragma unroll
            for (int kk = 0; kk < 2; ++kk) {
                short8 af[2], bfr[4];
                #pragma unroll
                for (int t = 0; t < 2; ++t) {
                    const int row = m0 + t * 16 + l16;
                    const int ph  = (kk * 4 + quad) ^ (row & 7);
                    af[t] = *reinterpret_cast<const short8*>(Ft[buf] + row * 64 + ph * 8);
                }
                #pragma unroll
                for (int u = 0; u < 4; ++u) {
                    const int wrow = col0 + u * 16 + l16;
                    const int ph   = (kk * 4 + quad) ^ (wrow & 7);
                    bfr[u] = *reinterpret_cast<const short8*>(Wt[buf] + wrow * 64 + ph * 8);
                }
                #pragma unroll
                for (int t = 0; t < 2; ++t)
                    #pragma unroll
                    for (int u = 0; u < 4; ++u)
                        acc[t][u] = __builtin_amdgcn_mfma_f32_16x16x32_bf16(af[t], bfr[u], acc[t][u], 0, 0, 0);
            }
            __syncthreads();
        }
    } else {
        _Float16* FtH0 = (_Float16*)Ft[0];
        _Float16* FtH1 = (_Float16*)Ft[1];
        _Float16* WtH0 = (_Float16*)Wt[0];
        _Float16* WtH1 = (_Float16*)Wt[1];

        const int frow = tid >> 3;                 // 0..63
        const int fseg = tid & 7;                  // 0..7
        const int fph  = fseg ^ (frow & 7);        // phys slot

        auto STAGE = [&](int kb, int buf) {
            const int k0 = kb * 64;
            _Float16* Wth = buf ? WtH1 : WtH0;
            _Float16* Fth = buf ? FtH1 : FtH0;
            #pragma unroll
            for (int j = 0; j < 4; ++j) {
                const int c = wave * 4 + j;
                const _Float16* Wh = (c < 16) ? Wq_h : Wk_h;
                const int wrow = (c & 15) * 8 + srow;
                load_lds16(Wh + (long)wrow * C_ + k0 + skoff,
                           Wth + c * 512 + lane * 8);
            }
            F8 x = load8(Fraw, (r0 + frow) * (long)C_ + k0 + fseg * 8, 0);
            half8 h;
            #pragma unroll
            for (int j = 0; j < 8; ++j) h[j] = (_Float16)x.v[j];
            *reinterpret_cast<half8*>(Fth + frow * 64 + fph * 8) = h;
        };

        STAGE(0, 0);
        __syncthreads();
        for (int kb = 0; kb < 16; ++kb) {
            const int buf = kb & 1;
            if (kb < 15) STAGE(kb + 1, buf ^ 1);
            _Float16* Wth = buf ? WtH1 : WtH0;
            _Float16* Fth = buf ? FtH1 : FtH0;
            #pragma unroll
            for (int kk = 0; kk < 2; ++kk) {
                half8 af[2], bfr[4];
                #pragma unroll
                for (int t = 0; t < 2; ++t) {
                    const int row = m0 + t * 16 + l16;
                    const int ph  = (kk * 4 + quad) ^ (row & 7);
                    af[t] = *reinterpret_cast<const half8*>(Fth + row * 64 + ph * 8);
                }
                #pragma unroll
                for (int u = 0; u < 4; ++u) {
                    const int wrow = col0 + u * 16 + l16;
                    const int ph   = (kk * 4 + quad) ^ (wrow & 7);
                    bfr[u] = *reinterpret_cast<const half8*>(Wth + wrow * 64 + ph * 8);
                }
                #pragma unroll
                for (int t = 0; t < 2; ++t)
                    #pragma unroll
                    for (int u = 0; u < 4; ++u)
                        acc[t][u] = __builtin_amdgcn_mfma_f32_16x16x32_f16(af[t], bfr[u], acc[t][u], 0, 0, 0);
            }
            __syncthreads();
        }
    }

    const bool isK = (col0 >= 128);
    const void* braw = isK ? bk_raw : bq_raw;
    _Float16* Out    = isK ? K : Q;
    #pragma unroll
    for (int u = 0; u < 4; ++u) {
        const int d = (col0 + u * 16 + l16) & 127;
        const float bv = bias_at(braw, d, is_bf16);
        #pragma unroll
        for (int t = 0; t < 2; ++t)
            #pragma unroll
            for (int r = 0; r < 4; ++r) {
                const long row = r0 + m0 + t * 16 + quad * 4 + r;
                Out[row * D_ + d] = (_Float16)(acc[t][u][r] + bv);
            }
    }
}

// ---------------------------------------------------------------------------
// Kernel 2 (FUSED attn+xm) — round-2 structure (measured 92.9us, no spill)
// with ONE spill-safe change: kf[4] loaded BATCHED at chunk top (round 2
// issued them serially inside the E^T loop -> 4 exposed ~300cyc L2 stalls
// per chunk). kf's live range ends before the barrier (no cross-chunk
// prefetch — that variant spilled, r7: WRITE 33->80MB). The `#pragma
// unroll 2` on the ch loop is REMOVED to halve al[4][4] live-range
// pressure (pays for kf[4]'s +16 regs).
// Spill tripwire for post-mortem: WRITE_SIZE must stay ~32.8MB.
// ---------------------------------------------------------------------------
__global__ __launch_bounds__(512, 2) void fused_attn_xm_kernel(
    const void* __restrict__ Lraw,   // [B,L,N] raw (bf16 world)
    const short* __restrict__ Lcvt,  // [B,L,N] bf16 bits (fp32 world)
    const _Float16* __restrict__ Q,  // [B,N,D] fp16
    const _Float16* __restrict__ K,  // [B,N,D] fp16
    void* __restrict__ OutRaw,
    const int* __restrict__ flag)
{
    const int is_bf16 = *flag;
    const int f    = blockIdx.y * 32 + blockIdx.x;   // flat dispatch index
    const int b    = f & 7;                           // XCD-affinity: batch = f % 8
    const int m0   = (f >> 3) * 64;                   // m-tile base
    const int wave = threadIdx.x >> 6;
    const int lane = threadIdx.x & 63;
    const int quad = lane >> 4;
    const int l16  = lane & 15;

    __shared__ short P0[64 * 128];   // 16 KB
    __shared__ short P1[64 * 128];   // 16 KB
    __shared__ float Zs[64];

    if (threadIdx.x < 64) Zs[threadIdx.x] = 0.0f;

    const short*    Lb = (is_bf16 ? (const short*)Lraw : Lcvt) + (long)b * L_ * N_;
    const _Float16* Qb = Q + (long)b * N_ * D_;
    const _Float16* Kb = K + (long)b * N_ * D_;

    // Q fragments (B-operand of E^T): m = m0 + u*16 + l16, d = s*32 + quad*8
    half8 bq[4][4];
    #pragma unroll
    for (int u = 0; u < 4; ++u)
        #pragma unroll
        for (int s = 0; s < 4; ++s)
            bq[u][s] = *reinterpret_cast<const half8*>(
                Qb + (long)(m0 + u * 16 + l16) * D_ + s * 32 + quad * 8);

    const int lw  = wave * 64;        // this wave's l-rows
    const int swz = l16 * 2;          // even XOR keeps 16B accesses contiguous
    const short* Lw = Lb + (long)(lw + l16) * N_ + quad * 8;           // logits base (incl quad*8)
    const _Float16* Kw = Kb + (long)(wave * 16 + l16) * D_ + quad * 8; // K base (incl quad*8)
    // P write slot: logical 8B slot = wave*4 + quad (n_local/4); phys = slot ^ swz
    const int pwr = ((wave * 4 + quad) ^ swz) << 2;

    floatx4 acc[4][4] = {};           // [t: l-frag][u: m-frag]
    float zpart[4] = {};

    for (int ch = 0; ch < 16; ++ch) {
        const int n0 = ch * 128;
        short* Pb = (ch & 1) ? P1 : P0;

        // ---- 1. K fragments BATCHED (4 back-to-back 16B loads; one latency)
        const _Float16* krow = Kw + (long)n0 * D_;
        half8 kf[4];
        #pragma unroll
        for (int s = 0; s < 4; ++s)
            kf[s] = *reinterpret_cast<const half8*>(krow + s * 32);

        // ---- 2. logits full-chunk preload (consumed after the barrier) ----
        // NOTE: Lw already includes quad*8 — do NOT add it again.
        short8 al[4][4];
        #pragma unroll
        for (int t = 0; t < 4; ++t)
            #pragma unroll
            for (int ks = 0; ks < 4; ++ks)
                al[t][ks] = *reinterpret_cast<const short8*>(
                    Lw + (long)t * 16 * N_ + n0 + ks * 32);

        // ---- 3. E^T: lane holds E[n0+wave*16+quad*4+r][m0+u*16+l16] ----
        floatx4 ae[4] = {};
        #pragma unroll
        for (int s = 0; s < 4; ++s)
            #pragma unroll
            for (int u = 0; u < 4; ++u)
                ae[u] = __builtin_amdgcn_mfma_f32_16x16x32_f16(kf[s], bq[u][s], ae[u], 0, 0, 0);

        // ---- 4. exp, Z partials, pack 4 consecutive-n bf16, swizzled write
        #pragma unroll
        for (int u = 0; u < 4; ++u) {
            short4v pk;
            #pragma unroll
            for (int r = 0; r < 4; ++r) {
                float e = __expf(ae[u][r]);
                zpart[u] += e;
                pk[r] = f2bf(e);
            }
            *reinterpret_cast<short4v*>(Pb + (u * 16 + l16) * 128 + pwr) = pk;
        }
        __syncthreads();   // write(ch) -> read(ch); dbuf covers read->next-write

        // ---- 5. out-GEMM: acc[t][u] += L[l, n-chunk] · P[m, n-chunk]^T ----
        #pragma unroll
        for (int ks = 0; ks < 4; ++ks) {
            short8 bp[4];
            #pragma unroll
            for (int u = 0; u < 4; ++u) {
                const int m = u * 16 + l16;
                bp[u] = *reinterpret_cast<const short8*>(
                    Pb + m * 128 + ((((ks * 8 + quad * 2) ^ swz)) << 2));
            }
            #pragma unroll
            for (int t = 0; t < 4; ++t)
                #pragma unroll
                for (int u = 0; u < 4; ++u)
                    acc[t][u] = __builtin_amdgcn_mfma_f32_16x16x32_bf16(
                        al[t][ks], bp[u], acc[t][u], 0, 0, 0);
        }
    }

    // ---- Z: reduce quads within wave, then waves via LDS atomics ----
    #pragma unroll
    for (int u = 0; u < 4; ++u) {
        float z = zpart[u];
        z += __shfl_xor(z, 16);
        z += __shfl_xor(z, 32);
        if (lane < 16) atomicAdd(&Zs[u * 16 + lane], z);
    }
    __syncthreads();

    float invz[4];
    #pragma unroll
    for (int u = 0; u < 4; ++u) invz[u] = 1.0f / Zs[u * 16 + l16];

    // ---- epilogue: divide by Z and store ----
    if (is_bf16) {
        short* Ob = (short*)OutRaw + (long)b * L_ * N_;
        #pragma unroll
        for (int t = 0; t < 4; ++t)
            #pragma unroll
            for (int u = 0; u < 4; ++u)
                #pragma unroll
                for (int r = 0; r < 4; ++r) {
                    const long row = lw + t * 16 + quad * 4 + r;
                    const int  col = m0 + u * 16 + l16;
                    Ob[row * N_ + col] = f2bf(acc[t][u][r] * invz[u]);
                }
    } else {
        float* Ob = (float*)OutRaw + (long)b * L_ * N_;
        #pragma unroll
        for (int t = 0; t < 4; ++t)
            #pragma unroll
            for (int u = 0; u < 4; ++u)
                #pragma unroll
                for (int r = 0; r < 4; ++r) {
                    const long row = lw + t * 16 + quad * 4 + r;
                    const int  col = m0 + u * 16 + l16;
                    Ob[row * N_ + col] = acc[t][u][r] * invz[u];
                }
    }
}

// ---------------------------------------------------------------------------
extern "C" void kernel_launch(void* const* d_in, const int* in_sizes, int n_in,
                              void* d_out, int out_size, void* d_ws, size_t ws_size,
                              hipStream_t stream) {
    const void* logits_raw = d_in[0];
    const void* feats_raw  = d_in[1];
    const void* wq_raw     = d_in[2];
    const void* bq_raw     = d_in[3];
    const void* wk_raw     = d_in[4];
    const void* bk_raw     = d_in[5];

    char* ws = (char*)d_ws;
    size_t off = 0;
    int* flag = (int*)(ws + off);           off += 256;
    short* logb = (short*)(ws + off);       off += (size_t)B_ * L_ * N_ * 2;   // 16 MB
    _Float16* Wq_h = (_Float16*)(ws + off); off += (size_t)D_ * C_ * 2;
    _Float16* Wk_h = (_Float16*)(ws + off); off += (size_t)D_ * C_ * 2;
    _Float16* Q = (_Float16*)(ws + off);    off += (size_t)B_ * N_ * D_ * 2;   // 4 MB
    _Float16* K = (_Float16*)(ws + off);    off += (size_t)B_ * N_ * D_ * 2;   // 4 MB

    hipLaunchKernelGGL(detect_kernel, dim3(1), dim3(64), 0, stream,
                       (const unsigned*)feats_raw, flag);
    hipLaunchKernelGGL(cvt_kernel, dim3((B_ * L_ * N_) / (256 * 8)), dim3(256), 0, stream,
                       logits_raw, logb, (long)B_ * L_ * N_, flag);
    hipLaunchKernelGGL(cvt_half2_kernel, dim3((D_ * C_) / (256 * 8), 2), dim3(256), 0, stream,
                       wq_raw, Wq_h, wk_raw, Wk_h, (long)D_ * C_, flag);
    hipLaunchKernelGGL(proj_kernel, dim3(B_ * N_ / 64), dim3(512), 0, stream,
                       feats_raw, wq_raw, wk_raw, Wq_h, Wk_h, bq_raw, bk_raw, Q, K, flag);
    hipLaunchKernelGGL(fused_attn_xm_kernel, dim3(N_ / 64, B_), dim3(512), 0, stream,
                       logits_raw, logb, Q, K, d_out, flag);
}

// Round 9
// 228.474 us; speedup vs baseline: 1.2297x; 1.0055x over previous
//
#include <hip/hip_runtime.h>
#include <hip/hip_bf16.h>

#define B_ 8
#define L_ 512
#define N_ 2048
#define C_ 1024
#define D_ 128

typedef __attribute__((ext_vector_type(8))) short    short8;   // 8 x bf16 bits
typedef __attribute__((ext_vector_type(4))) short    short4v;  // 4 x bf16 bits (8B)
typedef __attribute__((ext_vector_type(8))) _Float16 half8;
typedef __attribute__((ext_vector_type(4))) float    floatx4;

static __device__ __forceinline__ float s2f(short s) {
    return __uint_as_float(((unsigned)(unsigned short)s) << 16);
}
static __device__ __forceinline__ short f2bf(float f) {
    union { __hip_bfloat16 h; short s; } u;
    u.h = __float2bfloat16(f);
    return u.s;
}

struct F8 { float v[8]; };

static __device__ __forceinline__ F8 load8(const void* raw, long off, int is_bf16) {
    F8 r;
    if (is_bf16) {
        short8 x = *reinterpret_cast<const short8*>((const short*)raw + off);
        #pragma unroll
        for (int i = 0; i < 8; ++i) r.v[i] = s2f(x[i]);
    } else {
        const float* p = (const float*)raw + off;
        float4 a = *reinterpret_cast<const float4*>(p);
        float4 b = *reinterpret_cast<const float4*>(p + 4);
        r.v[0]=a.x; r.v[1]=a.y; r.v[2]=a.z; r.v[3]=a.w;
        r.v[4]=b.x; r.v[5]=b.y; r.v[6]=b.z; r.v[7]=b.w;
    }
    return r;
}

static __device__ __forceinline__ float bias_at(const void* raw, int d, int is_bf16) {
    return is_bf16 ? s2f(((const short*)raw)[d]) : ((const float*)raw)[d];
}

static __device__ __forceinline__ void load_lds16(const void* g, void* l) {
    __builtin_amdgcn_global_load_lds(
        (const __attribute__((address_space(1))) void*)g,
        (__attribute__((address_space(3))) void*)l, 16, 0, 0);
}

// ---------------------------------------------------------------------------
// In-block dtype detection (replaces the detect_kernel dispatch).
// All threads call; returns the same value in every thread. Contains one
// __syncthreads. Logic identical to the old detect_kernel.
// ---------------------------------------------------------------------------
static __device__ __forceinline__ int detect_flag(const unsigned* __restrict__ w) {
    __shared__ int sflag;
    const int tid = threadIdx.x;
    if (tid < 64) {
        int cnt = 0;
        for (int i = tid; i < 256; i += 64) {
            float lowv = __uint_as_float(w[i] << 16);
            float a = fabsf(lowv);
            if (a >= 1e-5f && a <= 100.0f) cnt++;
        }
        #pragma unroll
        for (int off = 32; off; off >>= 1) cnt += __shfl_down(cnt, off);
        if (tid == 0) sflag = (cnt > 128) ? 1 : 0;
    }
    __syncthreads();
    return sflag;
}

// ---------------------------------------------------------------------------
// fp32 world only: ONE kernel converts logits->bf16 and both weights->fp16.
// Flat block ranges: [0,4096) logits, [4096,4160) Wq, [4160,4224) Wk.
// ---------------------------------------------------------------------------
__global__ __launch_bounds__(256) void cvtall_kernel(
    const unsigned* __restrict__ dw,      // feats words for detection
    const void* __restrict__ logits_raw, short* __restrict__ logb,
    const void* __restrict__ wq_raw, _Float16* __restrict__ Wq_h,
    const void* __restrict__ wk_raw, _Float16* __restrict__ Wk_h)
{
    const int fl = detect_flag(dw);
    if (fl) return;                       // bf16 world: nothing to convert
    const long LBLK = (long)B_ * L_ * N_ / (256 * 8);   // 4096
    const long WBLK = (long)D_ * C_ / (256 * 8);        // 64
    const long blk = blockIdx.x;
    if (blk < LBLK) {
        long i = blk * 2048 + (long)threadIdx.x * 8;
        F8 x = load8(logits_raw, i, 0);
        short8 o;
        #pragma unroll
        for (int j = 0; j < 8; ++j) o[j] = f2bf(x.v[j]);
        *reinterpret_cast<short8*>(logb + i) = o;
    } else if (blk < LBLK + WBLK) {
        long i = (blk - LBLK) * 2048 + (long)threadIdx.x * 8;
        F8 x = load8(wq_raw, i, 0);
        half8 o;
        #pragma unroll
        for (int j = 0; j < 8; ++j) o[j] = (_Float16)x.v[j];
        *reinterpret_cast<half8*>(Wq_h + i) = o;
    } else {
        long i = (blk - LBLK - WBLK) * 2048 + (long)threadIdx.x * 8;
        F8 x = load8(wk_raw, i, 0);
        half8 o;
        #pragma unroll
        for (int j = 0; j < 8; ++j) o[j] = (_Float16)x.v[j];
        *reinterpret_cast<half8*>(Wk_h + i) = o;
    }
}

// ---------------------------------------------------------------------------
// Kernel 1: Q|K projection, SPLIT by blockIdx.y (0=Q, 1=K) for 2 blocks/CU.
// Per block: 64 F-rows x 128 W-rows, BK=64, double-buffered LDS (48KB),
// ONE barrier per K-step. Grid (256,2) = 512 blocks = 2 independent barrier
// domains per CU; __launch_bounds__(512,4) caps VGPR at 128 (natural use
// ~70 -> no spill, unlike the r3 fused attempt at ~220).
// ---------------------------------------------------------------------------
__global__ __launch_bounds__(512, 4) void proj_kernel(
    const void* __restrict__ Fraw,
    const void* __restrict__ Wq_raw, const void* __restrict__ Wk_raw,
    const _Float16* __restrict__ Wq_h, const _Float16* __restrict__ Wk_h,
    const void* __restrict__ bq_raw, const void* __restrict__ bk_raw,
    _Float16* __restrict__ Q, _Float16* __restrict__ K)
{
    const int is_bf16 = detect_flag((const unsigned*)Fraw);
    const int isK  = blockIdx.y;
    const int tid  = threadIdx.x;
    const int wave = tid >> 6;
    const int lane = tid & 63;
    const int quad = lane >> 4;
    const int l16  = lane & 15;
    const long r0  = (long)blockIdx.x * 64;

    const int m0   = (wave & 1) * 32;    // F rows within tile (2 frags)
    const int col0 = (wave >> 1) * 32;   // W rows within 128 (2 frags)

    __shared__ short Ft[2][64 * 64];     // 2 x 8 KB
    __shared__ short Wt[2][128 * 64];    // 2 x 16 KB  -> 48 KB total

    floatx4 acc[2][2] = {};

    // staging lane map: 8-row chunks of 64 shorts; lane covers row srow,
    // phys 16B slot sslot; fetch logical group sslot^srow (source swizzle).
    const int srow  = lane >> 3;         // 0..7
    const int sslot = lane & 7;          // 0..7
    const int skoff = (sslot ^ srow) * 8;

    if (is_bf16) {
        const short* Fr = (const short*)Fraw;
        const short* Wr = (const short*)(isK ? Wk_raw : Wq_raw);

        auto STAGE = [&](int kb, int buf) {
            const int k0 = kb * 64;
            // W: 16 chunks of 8 rows; wave stages chunks wave*2, wave*2+1
            #pragma unroll
            for (int j = 0; j < 2; ++j) {
                const int c = wave * 2 + j;               // 0..15
                const int wrow = c * 8 + srow;            // 0..127
                load_lds16(Wr + (long)wrow * C_ + k0 + skoff,
                           Wt[buf] + c * 512 + lane * 8);
            }
            // F: 8 chunks of 8 rows; wave stages chunk `wave`
            load_lds16(Fr + (r0 + wave * 8 + srow) * (long)C_ + k0 + skoff,
                       Ft[buf] + wave * 512 + lane * 8);
        };

        STAGE(0, 0);
        __syncthreads();
        for (int kb = 0; kb < 16; ++kb) {
            const int buf = kb & 1;
            if (kb < 15) STAGE(kb + 1, buf ^ 1);
            #pragma unroll
            for (int kk = 0; kk < 2; ++kk) {
                short8 af[2], bfr[2];
                #pragma unroll
                for (int t = 0; t < 2; ++t) {
                    const int row = m0 + t * 16 + l16;
                    const int ph  = (kk * 4 + quad) ^ (row & 7);
                    af[t] = *reinterpret_cast<const short8*>(Ft[buf] + row * 64 + ph * 8);
                }
                #pragma unroll
                for (int u = 0; u < 2; ++u) {
                    const int wrow = col0 + u * 16 + l16;
                    const int ph   = (kk * 4 + quad) ^ (wrow & 7);
                    bfr[u] = *reinterpret_cast<const short8*>(Wt[buf] + wrow * 64 + ph * 8);
                }
                #pragma unroll
                for (int t = 0; t < 2; ++t)
                    #pragma unroll
                    for (int u = 0; u < 2; ++u)
                        acc[t][u] = __builtin_amdgcn_mfma_f32_16x16x32_bf16(af[t], bfr[u], acc[t][u], 0, 0, 0);
            }
            __syncthreads();
        }

        const void* braw = isK ? bk_raw : bq_raw;
        _Float16* Out    = isK ? K : Q;
        #pragma unroll
        for (int u = 0; u < 2; ++u) {
            const int d = col0 + u * 16 + l16;           // 0..127
            const float bv = bias_at(braw, d, 1);
            #pragma unroll
            for (int t = 0; t < 2; ++t)
                #pragma unroll
                for (int r = 0; r < 4; ++r) {
                    const long row = r0 + m0 + t * 16 + quad * 4 + r;
                    Out[row * D_ + d] = (_Float16)(acc[t][u][r] + bv);
                }
        }
    } else {
        const _Float16* Wh = isK ? Wk_h : Wq_h;
        _Float16* FtH0 = (_Float16*)Ft[0];
        _Float16* FtH1 = (_Float16*)Ft[1];
        _Float16* WtH0 = (_Float16*)Wt[0];
        _Float16* WtH1 = (_Float16*)Wt[1];

        // F register-staging map: 8 threads per row, 8 fp32 (=16B out) each
        const int frow = tid >> 3;                 // 0..63
        const int fseg = tid & 7;                  // 0..7
        const int fph  = fseg ^ (frow & 7);        // phys slot

        auto STAGE = [&](int kb, int buf) {
            const int k0 = kb * 64;
            _Float16* Wth = buf ? WtH1 : WtH0;
            _Float16* Fth = buf ? FtH1 : FtH0;
            #pragma unroll
            for (int j = 0; j < 2; ++j) {
                const int c = wave * 2 + j;
                const int wrow = c * 8 + srow;
                load_lds16(Wh + (long)wrow * C_ + k0 + skoff,
                           Wth + c * 512 + lane * 8);
            }
            F8 x = load8(Fraw, (r0 + frow) * (long)C_ + k0 + fseg * 8, 0);
            half8 h;
            #pragma unroll
            for (int j = 0; j < 8; ++j) h[j] = (_Float16)x.v[j];
            *reinterpret_cast<half8*>(Fth + frow * 64 + fph * 8) = h;
        };

        STAGE(0, 0);
        __syncthreads();
        for (int kb = 0; kb < 16; ++kb) {
            const int buf = kb & 1;
            if (kb < 15) STAGE(kb + 1, buf ^ 1);
            _Float16* Wth = buf ? WtH1 : WtH0;
            _Float16* Fth = buf ? FtH1 : FtH0;
            #pragma unroll
            for (int kk = 0; kk < 2; ++kk) {
                half8 af[2], bfr[2];
                #pragma unroll
                for (int t = 0; t < 2; ++t) {
                    const int row = m0 + t * 16 + l16;
                    const int ph  = (kk * 4 + quad) ^ (row & 7);
                    af[t] = *reinterpret_cast<const half8*>(Fth + row * 64 + ph * 8);
                }
                #pragma unroll
                for (int u = 0; u < 2; ++u) {
                    const int wrow = col0 + u * 16 + l16;
                    const int ph   = (kk * 4 + quad) ^ (wrow & 7);
                    bfr[u] = *reinterpret_cast<const half8*>(Wth + wrow * 64 + ph * 8);
                }
                #pragma unroll
                for (int t = 0; t < 2; ++t)
                    #pragma unroll
                    for (int u = 0; u < 2; ++u)
                        acc[t][u] = __builtin_amdgcn_mfma_f32_16x16x32_f16(af[t], bfr[u], acc[t][u], 0, 0, 0);
            }
            __syncthreads();
        }

        const void* braw = isK ? bk_raw : bq_raw;
        _Float16* Out    = isK ? K : Q;
        #pragma unroll
        for (int u = 0; u < 2; ++u) {
            const int d = col0 + u * 16 + l16;
            const float bv = bias_at(braw, d, 0);
            #pragma unroll
            for (int t = 0; t < 2; ++t)
                #pragma unroll
                for (int r = 0; r < 4; ++r) {
                    const long row = r0 + m0 + t * 16 + quad * 4 + r;
                    Out[row * D_ + d] = (_Float16)(acc[t][u][r] + bv);
                }
        }
    }
}

// ---------------------------------------------------------------------------
// Kernel 2 (FUSED attn+xm) — round-8 structure UNCHANGED (measured 89.6us,
// no spill) except the flag dispatch is replaced by in-block detection.
// ---------------------------------------------------------------------------
__global__ __launch_bounds__(512, 2) void fused_attn_xm_kernel(
    const void* __restrict__ Lraw,   // [B,L,N] raw (bf16 world)
    const short* __restrict__ Lcvt,  // [B,L,N] bf16 bits (fp32 world)
    const _Float16* __restrict__ Q,  // [B,N,D] fp16
    const _Float16* __restrict__ K,  // [B,N,D] fp16
    void* __restrict__ OutRaw,
    const unsigned* __restrict__ dw) // feats words for detection
{
    const int f    = blockIdx.y * 32 + blockIdx.x;   // flat dispatch index
    const int b    = f & 7;                           // XCD-affinity: batch = f % 8
    const int m0   = (f >> 3) * 64;                   // m-tile base
    const int wave = threadIdx.x >> 6;
    const int lane = threadIdx.x & 63;
    const int quad = lane >> 4;
    const int l16  = lane & 15;

    __shared__ short P0[64 * 128];   // 16 KB
    __shared__ short P1[64 * 128];   // 16 KB
    __shared__ float Zs[64];

    if (threadIdx.x < 64) Zs[threadIdx.x] = 0.0f;
    const int is_bf16 = detect_flag(dw);   // contains a __syncthreads

    const short*    Lb = (is_bf16 ? (const short*)Lraw : Lcvt) + (long)b * L_ * N_;
    const _Float16* Qb = Q + (long)b * N_ * D_;
    const _Float16* Kb = K + (long)b * N_ * D_;

    // Q fragments (B-operand of E^T): m = m0 + u*16 + l16, d = s*32 + quad*8
    half8 bq[4][4];
    #pragma unroll
    for (int u = 0; u < 4; ++u)
        #pragma unroll
        for (int s = 0; s < 4; ++s)
            bq[u][s] = *reinterpret_cast<const half8*>(
                Qb + (long)(m0 + u * 16 + l16) * D_ + s * 32 + quad * 8);

    const int lw  = wave * 64;        // this wave's l-rows
    const int swz = l16 * 2;          // even XOR keeps 16B accesses contiguous
    const short* Lw = Lb + (long)(lw + l16) * N_ + quad * 8;           // logits base (incl quad*8)
    const _Float16* Kw = Kb + (long)(wave * 16 + l16) * D_ + quad * 8; // K base (incl quad*8)
    // P write slot: logical 8B slot = wave*4 + quad (n_local/4); phys = slot ^ swz
    const int pwr = ((wave * 4 + quad) ^ swz) << 2;

    floatx4 acc[4][4] = {};           // [t: l-frag][u: m-frag]
    float zpart[4] = {};

    for (int ch = 0; ch < 16; ++ch) {
        const int n0 = ch * 128;
        short* Pb = (ch & 1) ? P1 : P0;

        // ---- 1. K fragments BATCHED (4 back-to-back 16B loads; one latency)
        const _Float16* krow = Kw + (long)n0 * D_;
        half8 kf[4];
        #pragma unroll
        for (int s = 0; s < 4; ++s)
            kf[s] = *reinterpret_cast<const half8*>(krow + s * 32);

        // ---- 2. logits full-chunk preload (consumed after the barrier) ----
        // NOTE: Lw already includes quad*8 — do NOT add it again.
        short8 al[4][4];
        #pragma unroll
        for (int t = 0; t < 4; ++t)
            #pragma unroll
            for (int ks = 0; ks < 4; ++ks)
                al[t][ks] = *reinterpret_cast<const short8*>(
                    Lw + (long)t * 16 * N_ + n0 + ks * 32);

        // ---- 3. E^T: lane holds E[n0+wave*16+quad*4+r][m0+u*16+l16] ----
        floatx4 ae[4] = {};
        #pragma unroll
        for (int s = 0; s < 4; ++s)
            #pragma unroll
            for (int u = 0; u < 4; ++u)
                ae[u] = __builtin_amdgcn_mfma_f32_16x16x32_f16(kf[s], bq[u][s], ae[u], 0, 0, 0);

        // ---- 4. exp, Z partials, pack 4 consecutive-n bf16, swizzled write
        #pragma unroll
        for (int u = 0; u < 4; ++u) {
            short4v pk;
            #pragma unroll
            for (int r = 0; r < 4; ++r) {
                float e = __expf(ae[u][r]);
                zpart[u] += e;
                pk[r] = f2bf(e);
            }
            *reinterpret_cast<short4v*>(Pb + (u * 16 + l16) * 128 + pwr) = pk;
        }
        __syncthreads();   // write(ch) -> read(ch); dbuf covers read->next-write

        // ---- 5. out-GEMM: acc[t][u] += L[l, n-chunk] · P[m, n-chunk]^T ----
        #pragma unroll
        for (int ks = 0; ks < 4; ++ks) {
            short8 bp[4];
            #pragma unroll
            for (int u = 0; u < 4; ++u) {
                const int m = u * 16 + l16;
                bp[u] = *reinterpret_cast<const short8*>(
                    Pb + m * 128 + ((((ks * 8 + quad * 2) ^ swz)) << 2));
            }
            #pragma unroll
            for (int t = 0; t < 4; ++t)
                #pragma unroll
                for (int u = 0; u < 4; ++u)
                    acc[t][u] = __builtin_amdgcn_mfma_f32_16x16x32_bf16(
                        al[t][ks], bp[u], acc[t][u], 0, 0, 0);
        }
    }

    // ---- Z: reduce quads within wave, then waves via LDS atomics ----
    #pragma unroll
    for (int u = 0; u < 4; ++u) {
        float z = zpart[u];
        z += __shfl_xor(z, 16);
        z += __shfl_xor(z, 32);
        if (lane < 16) atomicAdd(&Zs[u * 16 + lane], z);
    }
    __syncthreads();

    float invz[4];
    #pragma unroll
    for (int u = 0; u < 4; ++u) invz[u] = 1.0f / Zs[u * 16 + l16];

    // ---- epilogue: divide by Z and store ----
    if (is_bf16) {
        short* Ob = (short*)OutRaw + (long)b * L_ * N_;
        #pragma unroll
        for (int t = 0; t < 4; ++t)
            #pragma unroll
            for (int u = 0; u < 4; ++u)
                #pragma unroll
                for (int r = 0; r < 4; ++r) {
                    const long row = lw + t * 16 + quad * 4 + r;
                    const int  col = m0 + u * 16 + l16;
                    Ob[row * N_ + col] = f2bf(acc[t][u][r] * invz[u]);
                }
    } else {
        float* Ob = (float*)OutRaw + (long)b * L_ * N_;
        #pragma unroll
        for (int t = 0; t < 4; ++t)
            #pragma unroll
            for (int u = 0; u < 4; ++u)
                #pragma unroll
                for (int r = 0; r < 4; ++r) {
                    const long row = lw + t * 16 + quad * 4 + r;
                    const int  col = m0 + u * 16 + l16;
                    Ob[row * N_ + col] = acc[t][u][r] * invz[u];
                }
    }
}

// ---------------------------------------------------------------------------
extern "C" void kernel_launch(void* const* d_in, const int* in_sizes, int n_in,
                              void* d_out, int out_size, void* d_ws, size_t ws_size,
                              hipStream_t stream) {
    const void* logits_raw = d_in[0];
    const void* feats_raw  = d_in[1];
    const void* wq_raw     = d_in[2];
    const void* bq_raw     = d_in[3];
    const void* wk_raw     = d_in[4];
    const void* bk_raw     = d_in[5];

    char* ws = (char*)d_ws;
    size_t off = 0;
    off += 256;                                          // (was flag; kept for layout)
    short* logb = (short*)(ws + off);       off += (size_t)B_ * L_ * N_ * 2;   // 16 MB
    _Float16* Wq_h = (_Float16*)(ws + off); off += (size_t)D_ * C_ * 2;
    _Float16* Wk_h = (_Float16*)(ws + off); off += (size_t)D_ * C_ * 2;
    _Float16* Q = (_Float16*)(ws + off);    off += (size_t)B_ * N_ * D_ * 2;   // 4 MB
    _Float16* K = (_Float16*)(ws + off);    off += (size_t)B_ * N_ * D_ * 2;   // 4 MB

    // 3 launches (was 5): cvtall -> proj -> fused
    hipLaunchKernelGGL(cvtall_kernel, dim3(4096 + 64 + 64), dim3(256), 0, stream,
                       (const unsigned*)feats_raw, logits_raw, logb,
                       wq_raw, Wq_h, wk_raw, Wk_h);
    hipLaunchKernelGGL(proj_kernel, dim3(B_ * N_ / 64, 2), dim3(512), 0, stream,
                       feats_raw, wq_raw, wk_raw, Wq_h, Wk_h, bq_raw, bk_raw, Q, K);
    hipLaunchKernelGGL(fused_attn_xm_kernel, dim3(N_ / 64, B_), dim3(512), 0, stream,
                       logits_raw, logb, Q, K, d_out, (const unsigned*)feats_raw);
}